// Round 2
// baseline (7494.192 us; speedup 1.0000x reference)
//
#include <hip/hip_runtime.h>
#include <hip/hip_bf16.h>

typedef __bf16 bf16;
typedef __bf16 bf16x8 __attribute__((ext_vector_type(8)));
typedef __bf16 bf16x4 __attribute__((ext_vector_type(4)));
typedef float  f32x4  __attribute__((ext_vector_type(4)));

// ---------------------------------------------------------------------------
// GEMM: C[M,N] = A[M,K] * B[N,K]^T (+bias[N]).  fp32 in/out, bf16 MFMA inside.
// ---------------------------------------------------------------------------
__global__ __launch_bounds__(256, 2)
void gemm_bt_kernel(const float* __restrict__ A, const float* __restrict__ B,
                    const float* __restrict__ bias, float* __restrict__ C,
                    int M, int N, int K, int lda, int ldb, int ldc)
{
    __shared__ bf16 As[64][72];
    __shared__ bf16 Bs[64][72];
    const int tid = threadIdx.x;
    const long bm = (long)blockIdx.y * 64;
    const long bn = (long)blockIdx.x * 64;
    const int w  = tid >> 6;
    const int l  = tid & 63;
    const int wm = (w >> 1) * 32, wn = (w & 1) * 32;
    const int lr = l & 15, lk = (l >> 4) * 8;

    const int srow = tid >> 2;
    const int scol = (tid & 3) * 16;
    const float* Ap = A + (bm + srow) * (long)lda + scol;
    const float* Bp = B + (bn + srow) * (long)ldb + scol;

    f32x4 acc[2][2];
    #pragma unroll
    for (int mi = 0; mi < 2; ++mi)
        #pragma unroll
        for (int ni = 0; ni < 2; ++ni)
            acc[mi][ni] = f32x4{0.f, 0.f, 0.f, 0.f};

    for (int kt = 0; kt < K; kt += 64) {
        #pragma unroll
        for (int i = 0; i < 16; i += 4) {
            float4 av = *reinterpret_cast<const float4*>(Ap + kt + i);
            float4 bv = *reinterpret_cast<const float4*>(Bp + kt + i);
            bf16x4 ac; ac[0] = (bf16)av.x; ac[1] = (bf16)av.y; ac[2] = (bf16)av.z; ac[3] = (bf16)av.w;
            bf16x4 bc; bc[0] = (bf16)bv.x; bc[1] = (bf16)bv.y; bc[2] = (bf16)bv.z; bc[3] = (bf16)bv.w;
            *reinterpret_cast<bf16x4*>(&As[srow][scol + i]) = ac;
            *reinterpret_cast<bf16x4*>(&Bs[srow][scol + i]) = bc;
        }
        __syncthreads();
        #pragma unroll
        for (int kk = 0; kk < 64; kk += 32) {
            bf16x8 a0 = *reinterpret_cast<const bf16x8*>(&As[wm +  0 + lr][kk + lk]);
            bf16x8 a1 = *reinterpret_cast<const bf16x8*>(&As[wm + 16 + lr][kk + lk]);
            bf16x8 b0 = *reinterpret_cast<const bf16x8*>(&Bs[wn +  0 + lr][kk + lk]);
            bf16x8 b1 = *reinterpret_cast<const bf16x8*>(&Bs[wn + 16 + lr][kk + lk]);
            acc[0][0] = __builtin_amdgcn_mfma_f32_16x16x32_bf16(a0, b0, acc[0][0], 0, 0, 0);
            acc[0][1] = __builtin_amdgcn_mfma_f32_16x16x32_bf16(a0, b1, acc[0][1], 0, 0, 0);
            acc[1][0] = __builtin_amdgcn_mfma_f32_16x16x32_bf16(a1, b0, acc[1][0], 0, 0, 0);
            acc[1][1] = __builtin_amdgcn_mfma_f32_16x16x32_bf16(a1, b1, acc[1][1], 0, 0, 0);
        }
        __syncthreads();
    }
    const int crow = wm + (l >> 4) * 4;
    const int ccol = wn + (l & 15);
    #pragma unroll
    for (int mi = 0; mi < 2; ++mi)
        #pragma unroll
        for (int ni = 0; ni < 2; ++ni) {
            long col = bn + ccol + ni * 16;
            float bv = bias ? bias[col] : 0.0f;
            #pragma unroll
            for (int r = 0; r < 4; ++r) {
                long row = bm + crow + mi * 16 + r;
                C[row * (long)ldc + col] = acc[mi][ni][r] + bv;
            }
        }
}

// ---------------------------------------------------------------------------
// Fused scan + flash-attention kernel. 512 threads.
//   blocks 0..55      : SSM scan (sync via monotonic per-step flag counters)
//   blocks 56..2103   : flash attention, one block = (b, head, 32 q-rows)
// ---------------------------------------------------------------------------
#define NBLK_SCAN 56

__device__ __forceinline__ void scan_body(const float* __restrict__ Amat,
                                          const float* __restrict__ xB,
                                          float* __restrict__ hs,
                                          unsigned int* __restrict__ ring,
                                          unsigned int* __restrict__ flags,
                                          float* hS)
{
    const int tid = threadIdx.x;
    const int bi  = blockIdx.x;
    const int kq  = tid & 31;      // 32 k-slices of 28
    const int rg  = tid >> 5;      // 16 rows per block
    const int row = bi * 16 + rg;

    float4 areg[7];
    {
        const float4* Ap = reinterpret_cast<const float4*>(Amat + (long)row * 896 + kq * 28);
        #pragma unroll
        for (int j = 0; j < 7; ++j) areg[j] = Ap[j];
    }

    for (int t = 1; t <= 1024; ++t) {
        if (t == 1) {
            for (int j = tid; j < 3584; j += 512) hS[j] = 0.0f;   // h0 = 0
        } else {
            if (tid == 0) {
                while (__hip_atomic_load(&flags[t - 1], __ATOMIC_ACQUIRE,
                                         __HIP_MEMORY_SCOPE_AGENT) < NBLK_SCAN) {
                    __builtin_amdgcn_s_sleep(1);
                }
            }
            __syncthreads();
            const unsigned int* src = ring + ((t - 1) & 7) * 3584;
            #pragma unroll
            for (int j = 0; j < 7; ++j) {   // 7 independent loads: one round-trip
                int idx = tid + j * 512;
                unsigned int v = __hip_atomic_load(&src[idx], __ATOMIC_RELAXED,
                                                   __HIP_MEMORY_SCOPE_AGENT);
                hS[idx] = __builtin_bit_cast(float, v);
            }
        }
        __syncthreads();

        const float4* h0p = reinterpret_cast<const float4*>(hS +    0 + kq * 28);
        const float4* h1p = reinterpret_cast<const float4*>(hS +  896 + kq * 28);
        const float4* h2p = reinterpret_cast<const float4*>(hS + 1792 + kq * 28);
        const float4* h3p = reinterpret_cast<const float4*>(hS + 2688 + kq * 28);
        float a0 = 0, a1 = 0, a2 = 0, a3 = 0;
        #pragma unroll
        for (int j = 0; j < 7; ++j) {
            float4 a = areg[j];
            float4 v0 = h0p[j]; a0 += a.x*v0.x + a.y*v0.y + a.z*v0.z + a.w*v0.w;
            float4 v1 = h1p[j]; a1 += a.x*v1.x + a.y*v1.y + a.z*v1.z + a.w*v1.w;
            float4 v2 = h2p[j]; a2 += a.x*v2.x + a.y*v2.y + a.z*v2.z + a.w*v2.w;
            float4 v3 = h3p[j]; a3 += a.x*v3.x + a.y*v3.y + a.z*v3.z + a.w*v3.w;
        }
        a0 += __shfl_xor(a0, 16); a1 += __shfl_xor(a1, 16); a2 += __shfl_xor(a2, 16); a3 += __shfl_xor(a3, 16);
        a0 += __shfl_xor(a0,  8); a1 += __shfl_xor(a1,  8); a2 += __shfl_xor(a2,  8); a3 += __shfl_xor(a3,  8);
        a0 += __shfl_xor(a0,  4); a1 += __shfl_xor(a1,  4); a2 += __shfl_xor(a2,  4); a3 += __shfl_xor(a3,  4);
        a0 += __shfl_xor(a0,  2); a1 += __shfl_xor(a1,  2); a2 += __shfl_xor(a2,  2); a3 += __shfl_xor(a3,  2);
        a0 += __shfl_xor(a0,  1); a1 += __shfl_xor(a1,  1); a2 += __shfl_xor(a2,  1); a3 += __shfl_xor(a3,  1);

        if (kq == 0) {
            unsigned int* dst = ring + (t & 7) * 3584;
            const long so = (long)(t - 1) * 896 + row;
            float z[4] = { a0 + xB[so],            a1 + xB[so +  917504],
                           a2 + xB[so + 1835008],  a3 + xB[so + 2752512] };
            #pragma unroll
            for (int b = 0; b < 4; ++b) {
                float zz = fminf(fmaxf(z[b], -15.f), 15.f);
                float e  = __expf(2.f * zz);
                float h  = (e - 1.f) / (e + 1.f);
                __hip_atomic_store(&dst[b * 896 + row], __builtin_bit_cast(unsigned int, h),
                                   __ATOMIC_RELAXED, __HIP_MEMORY_SCOPE_AGENT);
                hs[(long)b * 917504 + so] = h;
            }
        }
        __syncthreads();   // drains vmcnt: data stores complete before flag bump
        if (tid == 0)
            __hip_atomic_fetch_add(&flags[t], 1u, __ATOMIC_RELEASE, __HIP_MEMORY_SCOPE_AGENT);
    }
}

__device__ __forceinline__ void attn_body(const float* __restrict__ qkv,
                                          float* __restrict__ ctx,
                                          float* ldsf, int bid2)
{
    // LDS layout (f32 units): qS[32*56] | pS[32*66] | rS[32] | lS[32] | kS,vS bf16[64*60]
    float* qS = ldsf;
    float* pS = qS + 1792;
    float* rS = pS + 2112;
    float* lS = rS + 32;
    bf16*  kS = (bf16*)(lS + 32);
    bf16*  vS = kS + 3840;

    const int tid = threadIdx.x;
    const int qc = bid2 & 31;
    const int h  = (bid2 >> 5) & 15;
    const int b  = bid2 >> 9;
    const long base = (long)b * 1024 * 2688;
    const int q0 = qc * 32;
    const int hoff = h * 56;

    for (int idx = tid; idx < 1792; idx += 512) {
        int r = idx / 56, d = idx - r * 56;
        qS[idx] = qkv[base + (long)(q0 + r) * 2688 + hoff + d] * 0.13363062095621f;
    }

    const int w = tid >> 6, l = tid & 63;
    const int qrow = 4 * w;                 // score-phase rows qrow..qrow+3
    const int oq = tid >> 4, ods = tid & 15; // PV-phase (row, dim-slot)
    float m0 = -3e38f, m1 = -3e38f, m2 = -3e38f, m3 = -3e38f;
    float s_l0 = 0, s_l1 = 0, s_l2 = 0, s_l3 = 0;
    float o0 = 0, o1 = 0, o2 = 0, o3 = 0;

    for (int kt = 0; kt < 16; ++kt) {
        __syncthreads();
        for (int idx = tid; idx < 3584; idx += 512) {
            int r = idx / 56, d = idx - r * 56;
            long g = base + (long)(kt * 64 + r) * 2688 + hoff + d;
            kS[r * 60 + d] = (bf16)qkv[g + 896];
            vS[r * 60 + d] = (bf16)qkv[g + 1792];
        }
        __syncthreads();

        float s0 = 0, s1 = 0, s2 = 0, s3 = 0;
        const float* qp = qS + qrow * 56;
        const bf16* kp = kS + l * 60;
        #pragma unroll 8
        for (int d = 0; d < 56; ++d) {
            float kv = (float)kp[d];
            s0 += qp[d] * kv; s1 += qp[d + 56] * kv;
            s2 += qp[d + 112] * kv; s3 += qp[d + 168] * kv;
        }
        float x0 = s0, x1 = s1, x2 = s2, x3 = s3;
        #pragma unroll
        for (int off = 32; off >= 1; off >>= 1) {
            x0 = fmaxf(x0, __shfl_xor(x0, off));
            x1 = fmaxf(x1, __shfl_xor(x1, off));
            x2 = fmaxf(x2, __shfl_xor(x2, off));
            x3 = fmaxf(x3, __shfl_xor(x3, off));
        }
        float nm0 = fmaxf(m0, x0), nm1 = fmaxf(m1, x1);
        float nm2 = fmaxf(m2, x2), nm3 = fmaxf(m3, x3);
        float p0 = __expf(s0 - nm0), p1 = __expf(s1 - nm1);
        float p2 = __expf(s2 - nm2), p3 = __expf(s3 - nm3);
        float sc0 = __expf(m0 - nm0), sc1 = __expf(m1 - nm1);
        float sc2 = __expf(m2 - nm2), sc3 = __expf(m3 - nm3);
        float t0 = p0, t1 = p1, t2 = p2, t3 = p3;
        #pragma unroll
        for (int off = 32; off >= 1; off >>= 1) {
            t0 += __shfl_xor(t0, off); t1 += __shfl_xor(t1, off);
            t2 += __shfl_xor(t2, off); t3 += __shfl_xor(t3, off);
        }
        s_l0 = s_l0 * sc0 + t0; s_l1 = s_l1 * sc1 + t1;
        s_l2 = s_l2 * sc2 + t2; s_l3 = s_l3 * sc3 + t3;
        m0 = nm0; m1 = nm1; m2 = nm2; m3 = nm3;
        pS[(qrow + 0) * 66 + l] = p0; pS[(qrow + 1) * 66 + l] = p1;
        pS[(qrow + 2) * 66 + l] = p2; pS[(qrow + 3) * 66 + l] = p3;
        if (l == 0) { rS[qrow] = sc0; rS[qrow+1] = sc1; rS[qrow+2] = sc2; rS[qrow+3] = sc3; }
        __syncthreads();

        float rf = rS[oq];
        o0 *= rf; o1 *= rf; o2 *= rf; o3 *= rf;
        const float* pp = pS + oq * 66;
        #pragma unroll 4
        for (int kk = 0; kk < 64; ++kk) {
            float p = pp[kk];
            const bf16* vp = vS + kk * 60 + ods;
            o0 += p * (float)vp[0];
            o1 += p * (float)vp[16];
            o2 += p * (float)vp[32];
            if (ods < 8) o3 += p * (float)vp[48];
        }
    }
    __syncthreads();
    if (l == 0) {
        lS[qrow]     = 1.f / s_l0; lS[qrow + 1] = 1.f / s_l1;
        lS[qrow + 2] = 1.f / s_l2; lS[qrow + 3] = 1.f / s_l3;
    }
    __syncthreads();
    float inv = lS[oq];
    float* cp = ctx + ((long)b * 1024 + q0 + oq) * 896 + hoff + ods;
    cp[0]  = o0 * inv;
    cp[16] = o1 * inv;
    cp[32] = o2 * inv;
    if (ods < 8) cp[48] = o3 * inv;
}

__global__ __launch_bounds__(512)
void scan_attn_kernel(const float* __restrict__ Amat, const float* __restrict__ xB,
                      float* __restrict__ hs, unsigned int* __restrict__ ring,
                      unsigned int* __restrict__ flags,
                      const float* __restrict__ qkv, float* __restrict__ ctx)
{
    __shared__ float ldsf[7872];   // max(scan 3584, attn 1792+2112+64+3840*2*0.5)
    if (blockIdx.x < NBLK_SCAN)
        scan_body(Amat, xB, hs, ring, flags, ldsf);
    else
        attn_body(qkv, ctx, ldsf, blockIdx.x - NBLK_SCAN);
}

// ---------------------------------------------------------------------------
// Two LayerNorms -> packed "combined" buffer (4096 x 1792)
// ---------------------------------------------------------------------------
__global__ __launch_bounds__(256)
void ln2_kernel(const float* __restrict__ s_in, const float* __restrict__ a_in,
                const float* __restrict__ gs, const float* __restrict__ bs,
                const float* __restrict__ ga, const float* __restrict__ ba,
                float* __restrict__ comb)
{
    const int wv = threadIdx.x >> 6, ln = threadIdx.x & 63;
    const long row = (long)blockIdx.x * 4 + wv;
    const bool is_a = (blockIdx.y != 0);
    const float* src = (is_a ? a_in : s_in) + row * 896;
    float v[14]; float sum = 0, sq = 0;
    #pragma unroll
    for (int j = 0; j < 14; ++j) { v[j] = src[ln + j * 64]; sum += v[j]; sq += v[j] * v[j]; }
    #pragma unroll
    for (int off = 32; off >= 1; off >>= 1) { sum += __shfl_xor(sum, off); sq += __shfl_xor(sq, off); }
    const float mean = sum * (1.0f / 896.0f);
    const float var  = sq * (1.0f / 896.0f) - mean * mean;
    const float inv  = rsqrtf(var + 1e-5f);
    const float* g  = is_a ? ga : gs;
    const float* bb = is_a ? ba : bs;
    float* dst = comb + row * 1792 + (is_a ? 896 : 0);
    #pragma unroll
    for (int j = 0; j < 14; ++j) {
        int i = ln + j * 64;
        dst[i] = (v[j] - mean) * inv * g[i] + bb[i];
    }
}

// ---------------------------------------------------------------------------
// Gates + final mix -> d_out
// ---------------------------------------------------------------------------
__global__ __launch_bounds__(256)
void gate_mix_kernel(const float* __restrict__ fused, const float* __restrict__ gw,
                     const float* __restrict__ gb, const float* __restrict__ comb,
                     float* __restrict__ out)
{
    const int tid = threadIdx.x;
    const int seg = tid & 15;
    const long row = (long)blockIdx.x * 16 + (tid >> 4);
    const float* fr = fused + row * 896;
    float d0 = 0, d1 = 0;
    for (int i = seg; i < 896; i += 16) {
        float f = fr[i];
        d0 += f * gw[i];
        d1 += f * gw[896 + i];
    }
    #pragma unroll
    for (int off = 8; off >= 1; off >>= 1) { d0 += __shfl_xor(d0, off); d1 += __shfl_xor(d1, off); }
    float l0 = d0 + gb[0], l1 = d1 + gb[1];
    float m = fmaxf(l0, l1);
    float e0 = __expf(l0 - m), e1 = __expf(l1 - m);
    float inv = 1.0f / (e0 + e1);
    float g0 = e0 * inv, g1 = e1 * inv;
    const float* cr = comb + row * 1792;
    float* orow = out + row * 896;
    for (int i = seg; i < 896; i += 16)
        orow[i] = g0 * cr[i] + g1 * cr[896 + i];
}

// ---------------------------------------------------------------------------
extern "C" void kernel_launch(void* const* d_in, const int* in_sizes, int n_in,
                              void* d_out, int out_size, void* d_ws, size_t ws_size,
                              hipStream_t stream)
{
    (void)in_sizes; (void)n_in; (void)out_size; (void)ws_size;
    const float* x         = (const float*)d_in[0];
    const float* Amat      = (const float*)d_in[1];
    const float* Bm        = (const float*)d_in[2];
    const float* Cm        = (const float*)d_in[3];
    const float* ssm_in_w  = (const float*)d_in[4];
    const float* ssm_in_b  = (const float*)d_in[5];
    const float* ssm_out_w = (const float*)d_in[6];
    const float* ssm_out_b = (const float*)d_in[7];
    const float* qkv_w     = (const float*)d_in[8];
    const float* qkv_b     = (const float*)d_in[9];
    const float* attn_w    = (const float*)d_in[10];
    const float* attn_b    = (const float*)d_in[11];
    const float* proj_w    = (const float*)d_in[12];
    const float* proj_b    = (const float*)d_in[13];
    const float* ln_sg     = (const float*)d_in[14];
    const float* ln_sb     = (const float*)d_in[15];
    const float* ln_ag     = (const float*)d_in[16];
    const float* ln_ab     = (const float*)d_in[17];
    const float* fuse_w    = (const float*)d_in[18];
    const float* fuse_b    = (const float*)d_in[19];
    const float* gate_w    = (const float*)d_in[20];
    const float* gate_b    = (const float*)d_in[21];

    float* ws = (float*)d_ws;
    const long S0 = 0;          // xp, later ys           (4096x896)
    const long S1 = 3670016;    // xB, later t1           (4096x896)
    const long S2 = 7340032;    // qkv                    (4096x2688)
    const long S3 = 18350080;   // hs, later attn_out     (4096x896)
    const long S4 = 22020096;   // ssm_out, later fused   (4096x896)
    const long S5 = 25690112;   // combined               (4096x1792)
    const long S6 = 33030144;   // ctx                    (4096x896)
    const long S7 = 36700160;   // h ring (8x3584 f32)
    const long S8 = S7 + 28672; // flags (1025 u32)

    unsigned int* ring  = (unsigned int*)(ws + S7);
    unsigned int* flags = (unsigned int*)(ws + S8);

    dim3 g896(14, 64), gqkv(42, 64);

    hipMemsetAsync(flags, 0, 1025 * sizeof(unsigned int), stream);

    // independent front GEMMs
    gemm_bt_kernel<<<g896, 256, 0, stream>>>(x, ssm_in_w, ssm_in_b, ws + S0, 4096, 896, 896, 896, 896, 896);
    gemm_bt_kernel<<<g896, 256, 0, stream>>>(ws + S0, Bm, nullptr, ws + S1, 4096, 896, 896, 896, 896, 896);
    gemm_bt_kernel<<<gqkv, 256, 0, stream>>>(x, qkv_w, qkv_b, ws + S2, 4096, 2688, 896, 896, 896, 2688);
    // fused: scan (blocks 0..55) + flash attention (blocks 56..2103)
    scan_attn_kernel<<<NBLK_SCAN + 2048, 512, 0, stream>>>(
        Amat, ws + S1, ws + S3, ring, flags, ws + S2, ws + S6);
    // SSM tail
    gemm_bt_kernel<<<g896, 256, 0, stream>>>(ws + S3, Cm, nullptr, ws + S0, 4096, 896, 896, 896, 896, 896);
    gemm_bt_kernel<<<g896, 256, 0, stream>>>(ws + S0, ssm_out_w, ssm_out_b, ws + S4, 4096, 896, 896, 896, 896, 896);
    // attention tail
    gemm_bt_kernel<<<g896, 256, 0, stream>>>(ws + S6, attn_w, attn_b, ws + S1, 4096, 896, 896, 896, 896, 896);
    gemm_bt_kernel<<<g896, 256, 0, stream>>>(ws + S1, proj_w, proj_b, ws + S3, 4096, 896, 896, 896, 896, 896);
    // norms + mixer
    ln2_kernel<<<dim3(1024, 2), 256, 0, stream>>>(ws + S4, ws + S3, ln_sg, ln_sb, ln_ag, ln_ab, ws + S5);
    gemm_bt_kernel<<<g896, 256, 0, stream>>>(ws + S5, fuse_w, fuse_b, ws + S4, 4096, 896, 1792, 1792, 2688, 896);
    gate_mix_kernel<<<256, 256, 0, stream>>>(ws + S4, gate_w, gate_b, ws + S5, (float*)d_out);
}

// Round 3
// 3629.666 us; speedup vs baseline: 2.0647x; 2.0647x over previous
//
#include <hip/hip_runtime.h>
#include <hip/hip_bf16.h>

typedef __bf16 bf16;
typedef __bf16 bf16x8 __attribute__((ext_vector_type(8)));
typedef __bf16 bf16x4 __attribute__((ext_vector_type(4)));
typedef float  f32x4  __attribute__((ext_vector_type(4)));

// ---------------------------------------------------------------------------
// GEMM: C[M,N] = A[M,K] * B[N,K]^T (+bias[N]).  fp32 in/out, bf16 MFMA inside.
// ---------------------------------------------------------------------------
__global__ __launch_bounds__(256, 2)
void gemm_bt_kernel(const float* __restrict__ A, const float* __restrict__ B,
                    const float* __restrict__ bias, float* __restrict__ C,
                    int M, int N, int K, int lda, int ldb, int ldc)
{
    __shared__ bf16 As[64][72];
    __shared__ bf16 Bs[64][72];
    const int tid = threadIdx.x;
    const long bm = (long)blockIdx.y * 64;
    const long bn = (long)blockIdx.x * 64;
    const int w  = tid >> 6;
    const int l  = tid & 63;
    const int wm = (w >> 1) * 32, wn = (w & 1) * 32;
    const int lr = l & 15, lk = (l >> 4) * 8;

    const int srow = tid >> 2;
    const int scol = (tid & 3) * 16;
    const float* Ap = A + (bm + srow) * (long)lda + scol;
    const float* Bp = B + (bn + srow) * (long)ldb + scol;

    f32x4 acc[2][2];
    #pragma unroll
    for (int mi = 0; mi < 2; ++mi)
        #pragma unroll
        for (int ni = 0; ni < 2; ++ni)
            acc[mi][ni] = f32x4{0.f, 0.f, 0.f, 0.f};

    for (int kt = 0; kt < K; kt += 64) {
        #pragma unroll
        for (int i = 0; i < 16; i += 4) {
            float4 av = *reinterpret_cast<const float4*>(Ap + kt + i);
            float4 bv = *reinterpret_cast<const float4*>(Bp + kt + i);
            bf16x4 ac; ac[0] = (bf16)av.x; ac[1] = (bf16)av.y; ac[2] = (bf16)av.z; ac[3] = (bf16)av.w;
            bf16x4 bc; bc[0] = (bf16)bv.x; bc[1] = (bf16)bv.y; bc[2] = (bf16)bv.z; bc[3] = (bf16)bv.w;
            *reinterpret_cast<bf16x4*>(&As[srow][scol + i]) = ac;
            *reinterpret_cast<bf16x4*>(&Bs[srow][scol + i]) = bc;
        }
        __syncthreads();
        #pragma unroll
        for (int kk = 0; kk < 64; kk += 32) {
            bf16x8 a0 = *reinterpret_cast<const bf16x8*>(&As[wm +  0 + lr][kk + lk]);
            bf16x8 a1 = *reinterpret_cast<const bf16x8*>(&As[wm + 16 + lr][kk + lk]);
            bf16x8 b0 = *reinterpret_cast<const bf16x8*>(&Bs[wn +  0 + lr][kk + lk]);
            bf16x8 b1 = *reinterpret_cast<const bf16x8*>(&Bs[wn + 16 + lr][kk + lk]);
            acc[0][0] = __builtin_amdgcn_mfma_f32_16x16x32_bf16(a0, b0, acc[0][0], 0, 0, 0);
            acc[0][1] = __builtin_amdgcn_mfma_f32_16x16x32_bf16(a0, b1, acc[0][1], 0, 0, 0);
            acc[1][0] = __builtin_amdgcn_mfma_f32_16x16x32_bf16(a1, b0, acc[1][0], 0, 0, 0);
            acc[1][1] = __builtin_amdgcn_mfma_f32_16x16x32_bf16(a1, b1, acc[1][1], 0, 0, 0);
        }
        __syncthreads();
    }
    const int crow = wm + (l >> 4) * 4;
    const int ccol = wn + (l & 15);
    #pragma unroll
    for (int mi = 0; mi < 2; ++mi)
        #pragma unroll
        for (int ni = 0; ni < 2; ++ni) {
            long col = bn + ccol + ni * 16;
            float bv = bias ? bias[col] : 0.0f;
            #pragma unroll
            for (int r = 0; r < 4; ++r) {
                long row = bm + crow + mi * 16 + r;
                C[row * (long)ldc + col] = acc[mi][ni][r] + bv;
            }
        }
}

// ---------------------------------------------------------------------------
// SSM scan v3: data-is-the-flag directly on the hs output buffer.
// hs (4,1024,896) is pre-filled with 0xFFFFFFFF (NaN; tanh output can never
// have this bit pattern). Readers spin with 7 INDEPENDENT parallel agent-scope
// loads per iteration (one coherence round-trip per iteration, not 7 serial
// ones -- the round-1 mistake). No flags, no RMW hotspot, no resets.
// ---------------------------------------------------------------------------
#define SENT 0xFFFFFFFFu

__global__ __launch_bounds__(512)
void ssm_scan_kernel(const float* __restrict__ Amat,
                     const float* __restrict__ xB,     // (4,1024,896)
                     float* __restrict__ hs)           // (4,1024,896) sentinel-filled
{
    __shared__ float hS[3584];
    const int tid = threadIdx.x;
    const int bi  = blockIdx.x;
    const int kq  = tid & 31;      // 32 k-slices of 28
    const int rg  = tid >> 5;      // 16 rows per block
    const int row = bi * 16 + rg;

    float4 areg[7];
    {
        const float4* Ap = reinterpret_cast<const float4*>(Amat + (long)row * 896 + kq * 28);
        #pragma unroll
        for (int j = 0; j < 7; ++j) areg[j] = Ap[j];
    }

    // fixed (batch, dim) offset for each of this thread's 7 staging words
    long poff[7];
    #pragma unroll
    for (int j = 0; j < 7; ++j) {
        int idx = tid + j * 512;
        int b = idx / 896;
        int d = idx - b * 896;
        poff[j] = (long)b * 917504 + d;
    }
    const unsigned int* hsrc = (const unsigned int*)hs;
    unsigned int* hdst = (unsigned int*)hs;

    for (int t = 1; t <= 1024; ++t) {
        const long so = (long)(t - 1) * 896 + row;
        float xb0 = 0, xb1 = 0, xb2 = 0, xb3 = 0;
        if (kq == 0) {   // prefetch input drive: overlaps the poll below
            xb0 = xB[so];
            xb1 = xB[so +  917504];
            xb2 = xB[so + 1835008];
            xb3 = xB[so + 2752512];
        }

        if (t == 1) {
            #pragma unroll
            for (int j = 0; j < 7; ++j) hS[tid + j * 512] = 0.0f;   // h0 = 0
        } else {
            const long sb = (long)(t - 2) * 896;
            unsigned int v[7];
            for (;;) {
                bool ok = true;
                #pragma unroll
                for (int j = 0; j < 7; ++j)
                    v[j] = __hip_atomic_load(&hsrc[sb + poff[j]], __ATOMIC_RELAXED,
                                             __HIP_MEMORY_SCOPE_AGENT);
                #pragma unroll
                for (int j = 0; j < 7; ++j) ok &= (v[j] != SENT);
                if (ok) break;
            }
            #pragma unroll
            for (int j = 0; j < 7; ++j) hS[tid + j * 512] = __builtin_bit_cast(float, v[j]);
        }
        __syncthreads();

        const float4* h0p = reinterpret_cast<const float4*>(hS +    0 + kq * 28);
        const float4* h1p = reinterpret_cast<const float4*>(hS +  896 + kq * 28);
        const float4* h2p = reinterpret_cast<const float4*>(hS + 1792 + kq * 28);
        const float4* h3p = reinterpret_cast<const float4*>(hS + 2688 + kq * 28);
        float a0 = 0, a1 = 0, a2 = 0, a3 = 0;
        #pragma unroll
        for (int j = 0; j < 7; ++j) {
            float4 a = areg[j];
            float4 v0 = h0p[j]; a0 += a.x*v0.x + a.y*v0.y + a.z*v0.z + a.w*v0.w;
            float4 v1 = h1p[j]; a1 += a.x*v1.x + a.y*v1.y + a.z*v1.z + a.w*v1.w;
            float4 v2 = h2p[j]; a2 += a.x*v2.x + a.y*v2.y + a.z*v2.z + a.w*v2.w;
            float4 v3 = h3p[j]; a3 += a.x*v3.x + a.y*v3.y + a.z*v3.z + a.w*v3.w;
        }
        a0 += __shfl_xor(a0, 16); a1 += __shfl_xor(a1, 16); a2 += __shfl_xor(a2, 16); a3 += __shfl_xor(a3, 16);
        a0 += __shfl_xor(a0,  8); a1 += __shfl_xor(a1,  8); a2 += __shfl_xor(a2,  8); a3 += __shfl_xor(a3,  8);
        a0 += __shfl_xor(a0,  4); a1 += __shfl_xor(a1,  4); a2 += __shfl_xor(a2,  4); a3 += __shfl_xor(a3,  4);
        a0 += __shfl_xor(a0,  2); a1 += __shfl_xor(a1,  2); a2 += __shfl_xor(a2,  2); a3 += __shfl_xor(a3,  2);
        a0 += __shfl_xor(a0,  1); a1 += __shfl_xor(a1,  1); a2 += __shfl_xor(a2,  1); a3 += __shfl_xor(a3,  1);

        if (kq == 0) {
            float z[4] = { a0 + xb0, a1 + xb1, a2 + xb2, a3 + xb3 };
            #pragma unroll
            for (int b = 0; b < 4; ++b) {
                float zz = fminf(fmaxf(z[b], -15.f), 15.f);
                float e  = __expf(2.f * zz);
                float h  = (e - 1.f) / (e + 1.f);
                __hip_atomic_store(&hdst[(long)b * 917504 + so],
                                   __builtin_bit_cast(unsigned int, h),
                                   __ATOMIC_RELAXED, __HIP_MEMORY_SCOPE_AGENT);
            }
        }
        __syncthreads();   // LDS WAR: next step's staging vs this step's reads
    }
}

// ---------------------------------------------------------------------------
// Flash attention: one block = (b, head, 32 q-rows). 512 threads.
// ---------------------------------------------------------------------------
__global__ __launch_bounds__(512)
void attn_kernel(const float* __restrict__ qkv, float* __restrict__ ctx)
{
    // LDS (f32 units): qS[32*56] | pS[32*66] | rS[32] | lS[32] | kS,vS bf16[64*60]
    __shared__ float ldsf[7872];
    float* qS = ldsf;
    float* pS = qS + 1792;
    float* rS = pS + 2112;
    float* lS = rS + 32;
    bf16*  kS = (bf16*)(lS + 32);
    bf16*  vS = kS + 3840;

    const int tid = threadIdx.x;
    const int bid2 = blockIdx.x;
    const int qc = bid2 & 31;
    const int h  = (bid2 >> 5) & 15;
    const int b  = bid2 >> 9;
    const long base = (long)b * 1024 * 2688;
    const int q0 = qc * 32;
    const int hoff = h * 56;

    for (int idx = tid; idx < 1792; idx += 512) {
        int r = idx / 56, d = idx - r * 56;
        qS[idx] = qkv[base + (long)(q0 + r) * 2688 + hoff + d] * 0.13363062095621f;
    }

    const int w = tid >> 6, l = tid & 63;
    const int qrow = 4 * w;                  // score-phase rows qrow..qrow+3
    const int oq = tid >> 4, ods = tid & 15; // PV-phase (row, dim-slot)
    float m0 = -3e38f, m1 = -3e38f, m2 = -3e38f, m3 = -3e38f;
    float s_l0 = 0, s_l1 = 0, s_l2 = 0, s_l3 = 0;
    float o0 = 0, o1 = 0, o2 = 0, o3 = 0;

    for (int kt = 0; kt < 16; ++kt) {
        __syncthreads();
        for (int idx = tid; idx < 3584; idx += 512) {
            int r = idx / 56, d = idx - r * 56;
            long g = base + (long)(kt * 64 + r) * 2688 + hoff + d;
            kS[r * 60 + d] = (bf16)qkv[g + 896];
            vS[r * 60 + d] = (bf16)qkv[g + 1792];
        }
        __syncthreads();

        float s0 = 0, s1 = 0, s2 = 0, s3 = 0;
        const float* qp = qS + qrow * 56;
        const bf16* kp = kS + l * 60;
        #pragma unroll 8
        for (int d = 0; d < 56; ++d) {
            float kv = (float)kp[d];
            s0 += qp[d] * kv; s1 += qp[d + 56] * kv;
            s2 += qp[d + 112] * kv; s3 += qp[d + 168] * kv;
        }
        float x0 = s0, x1 = s1, x2 = s2, x3 = s3;
        #pragma unroll
        for (int off = 32; off >= 1; off >>= 1) {
            x0 = fmaxf(x0, __shfl_xor(x0, off));
            x1 = fmaxf(x1, __shfl_xor(x1, off));
            x2 = fmaxf(x2, __shfl_xor(x2, off));
            x3 = fmaxf(x3, __shfl_xor(x3, off));
        }
        float nm0 = fmaxf(m0, x0), nm1 = fmaxf(m1, x1);
        float nm2 = fmaxf(m2, x2), nm3 = fmaxf(m3, x3);
        float p0 = __expf(s0 - nm0), p1 = __expf(s1 - nm1);
        float p2 = __expf(s2 - nm2), p3 = __expf(s3 - nm3);
        float sc0 = __expf(m0 - nm0), sc1 = __expf(m1 - nm1);
        float sc2 = __expf(m2 - nm2), sc3 = __expf(m3 - nm3);
        float t0 = p0, t1 = p1, t2 = p2, t3 = p3;
        #pragma unroll
        for (int off = 32; off >= 1; off >>= 1) {
            t0 += __shfl_xor(t0, off); t1 += __shfl_xor(t1, off);
            t2 += __shfl_xor(t2, off); t3 += __shfl_xor(t3, off);
        }
        s_l0 = s_l0 * sc0 + t0; s_l1 = s_l1 * sc1 + t1;
        s_l2 = s_l2 * sc2 + t2; s_l3 = s_l3 * sc3 + t3;
        m0 = nm0; m1 = nm1; m2 = nm2; m3 = nm3;
        pS[(qrow + 0) * 66 + l] = p0; pS[(qrow + 1) * 66 + l] = p1;
        pS[(qrow + 2) * 66 + l] = p2; pS[(qrow + 3) * 66 + l] = p3;
        if (l == 0) { rS[qrow] = sc0; rS[qrow+1] = sc1; rS[qrow+2] = sc2; rS[qrow+3] = sc3; }
        __syncthreads();

        float rf = rS[oq];
        o0 *= rf; o1 *= rf; o2 *= rf; o3 *= rf;
        const float* pp = pS + oq * 66;
        #pragma unroll 4
        for (int kk = 0; kk < 64; ++kk) {
            float p = pp[kk];
            const bf16* vp = vS + kk * 60 + ods;
            o0 += p * (float)vp[0];
            o1 += p * (float)vp[16];
            o2 += p * (float)vp[32];
            if (ods < 8) o3 += p * (float)vp[48];
        }
    }
    __syncthreads();
    if (l == 0) {
        lS[qrow]     = 1.f / s_l0; lS[qrow + 1] = 1.f / s_l1;
        lS[qrow + 2] = 1.f / s_l2; lS[qrow + 3] = 1.f / s_l3;
    }
    __syncthreads();
    float inv = lS[oq];
    float* cp = ctx + ((long)b * 1024 + q0 + oq) * 896 + hoff + ods;
    cp[0]  = o0 * inv;
    cp[16] = o1 * inv;
    cp[32] = o2 * inv;
    if (ods < 8) cp[48] = o3 * inv;
}

// ---------------------------------------------------------------------------
// Two LayerNorms -> packed "combined" buffer (4096 x 1792)
// ---------------------------------------------------------------------------
__global__ __launch_bounds__(256)
void ln2_kernel(const float* __restrict__ s_in, const float* __restrict__ a_in,
                const float* __restrict__ gs, const float* __restrict__ bs,
                const float* __restrict__ ga, const float* __restrict__ ba,
                float* __restrict__ comb)
{
    const int wv = threadIdx.x >> 6, ln = threadIdx.x & 63;
    const long row = (long)blockIdx.x * 4 + wv;
    const bool is_a = (blockIdx.y != 0);
    const float* src = (is_a ? a_in : s_in) + row * 896;
    float v[14]; float sum = 0, sq = 0;
    #pragma unroll
    for (int j = 0; j < 14; ++j) { v[j] = src[ln + j * 64]; sum += v[j]; sq += v[j] * v[j]; }
    #pragma unroll
    for (int off = 32; off >= 1; off >>= 1) { sum += __shfl_xor(sum, off); sq += __shfl_xor(sq, off); }
    const float mean = sum * (1.0f / 896.0f);
    const float var  = sq * (1.0f / 896.0f) - mean * mean;
    const float inv  = rsqrtf(var + 1e-5f);
    const float* g  = is_a ? ga : gs;
    const float* bb = is_a ? ba : bs;
    float* dst = comb + row * 1792 + (is_a ? 896 : 0);
    #pragma unroll
    for (int j = 0; j < 14; ++j) {
        int i = ln + j * 64;
        dst[i] = (v[j] - mean) * inv * g[i] + bb[i];
    }
}

// ---------------------------------------------------------------------------
// Gates + final mix -> d_out
// ---------------------------------------------------------------------------
__global__ __launch_bounds__(256)
void gate_mix_kernel(const float* __restrict__ fused, const float* __restrict__ gw,
                     const float* __restrict__ gb, const float* __restrict__ comb,
                     float* __restrict__ out)
{
    const int tid = threadIdx.x;
    const int seg = tid & 15;
    const long row = (long)blockIdx.x * 16 + (tid >> 4);
    const float* fr = fused + row * 896;
    float d0 = 0, d1 = 0;
    for (int i = seg; i < 896; i += 16) {
        float f = fr[i];
        d0 += f * gw[i];
        d1 += f * gw[896 + i];
    }
    #pragma unroll
    for (int off = 8; off >= 1; off >>= 1) { d0 += __shfl_xor(d0, off); d1 += __shfl_xor(d1, off); }
    float l0 = d0 + gb[0], l1 = d1 + gb[1];
    float m = fmaxf(l0, l1);
    float e0 = __expf(l0 - m), e1 = __expf(l1 - m);
    float inv = 1.0f / (e0 + e1);
    float g0 = e0 * inv, g1 = e1 * inv;
    const float* cr = comb + row * 1792;
    float* orow = out + row * 896;
    for (int i = seg; i < 896; i += 16)
        orow[i] = g0 * cr[i] + g1 * cr[896 + i];
}

// ---------------------------------------------------------------------------
extern "C" void kernel_launch(void* const* d_in, const int* in_sizes, int n_in,
                              void* d_out, int out_size, void* d_ws, size_t ws_size,
                              hipStream_t stream)
{
    (void)in_sizes; (void)n_in; (void)out_size; (void)ws_size;
    const float* x         = (const float*)d_in[0];
    const float* Amat      = (const float*)d_in[1];
    const float* Bm        = (const float*)d_in[2];
    const float* Cm        = (const float*)d_in[3];
    const float* ssm_in_w  = (const float*)d_in[4];
    const float* ssm_in_b  = (const float*)d_in[5];
    const float* ssm_out_w = (const float*)d_in[6];
    const float* ssm_out_b = (const float*)d_in[7];
    const float* qkv_w     = (const float*)d_in[8];
    const float* qkv_b     = (const float*)d_in[9];
    const float* attn_w    = (const float*)d_in[10];
    const float* attn_b    = (const float*)d_in[11];
    const float* proj_w    = (const float*)d_in[12];
    const float* proj_b    = (const float*)d_in[13];
    const float* ln_sg     = (const float*)d_in[14];
    const float* ln_sb     = (const float*)d_in[15];
    const float* ln_ag     = (const float*)d_in[16];
    const float* ln_ab     = (const float*)d_in[17];
    const float* fuse_w    = (const float*)d_in[18];
    const float* fuse_b    = (const float*)d_in[19];
    const float* gate_w    = (const float*)d_in[20];
    const float* gate_b    = (const float*)d_in[21];

    float* ws = (float*)d_ws;
    const long S0 = 0;          // xp, later ys           (4096x896)
    const long S1 = 3670016;    // xB, later t1           (4096x896)
    const long S2 = 7340032;    // qkv                    (4096x2688)
    const long S3 = 18350080;   // hs, later attn_out     (4096x896)
    const long S4 = 22020096;   // ssm_out, later fused   (4096x896)
    const long S5 = 25690112;   // combined               (4096x1792)
    const long S6 = 33030144;   // ctx                    (4096x896)

    dim3 g896(14, 64), gqkv(42, 64);

    // sentinel-fill hs: 0xFF bytes = NaN pattern, unreachable by tanh output
    hipMemsetAsync(ws + S3, 0xFF, 3670016 * sizeof(float), stream);

    // front GEMMs
    gemm_bt_kernel<<<g896, 256, 0, stream>>>(x, ssm_in_w, ssm_in_b, ws + S0, 4096, 896, 896, 896, 896, 896);
    gemm_bt_kernel<<<g896, 256, 0, stream>>>(ws + S0, Bm, nullptr, ws + S1, 4096, 896, 896, 896, 896, 896);
    gemm_bt_kernel<<<gqkv, 256, 0, stream>>>(x, qkv_w, qkv_b, ws + S2, 4096, 2688, 896, 896, 896, 2688);
    // attention (independent of scan; full GPU, clean fabric for scan after)
    attn_kernel<<<2048, 512, 0, stream>>>(ws + S2, ws + S6);
    // sequential scan -> hs
    ssm_scan_kernel<<<56, 512, 0, stream>>>(Amat, ws + S1, ws + S3);
    // SSM tail
    gemm_bt_kernel<<<g896, 256, 0, stream>>>(ws + S3, Cm, nullptr, ws + S0, 4096, 896, 896, 896, 896, 896);
    gemm_bt_kernel<<<g896, 256, 0, stream>>>(ws + S0, ssm_out_w, ssm_out_b, ws + S4, 4096, 896, 896, 896, 896, 896);
    // attention tail
    gemm_bt_kernel<<<g896, 256, 0, stream>>>(ws + S6, attn_w, attn_b, ws + S1, 4096, 896, 896, 896, 896, 896);
    gemm_bt_kernel<<<g896, 256, 0, stream>>>(ws + S1, proj_w, proj_b, ws + S3, 4096, 896, 896, 896, 896, 896);
    // norms + mixer
    ln2_kernel<<<dim3(1024, 2), 256, 0, stream>>>(ws + S4, ws + S3, ln_sg, ln_sb, ln_ag, ln_ab, ws + S5);
    gemm_bt_kernel<<<g896, 256, 0, stream>>>(ws + S5, fuse_w, fuse_b, ws + S4, 4096, 896, 1792, 1792, 2688, 896);
    gate_mix_kernel<<<256, 256, 0, stream>>>(ws + S4, gate_w, gate_b, ws + S5, (float*)d_out);
}